// Round 1
// 277.569 us; speedup vs baseline: 1.0533x; 1.0533x over previous
//
#include <hip/hip_runtime.h>
#include <stdint.h>

// DCT2D: y = Dh @ x @ Dw^T per (b,c); B=32,H=W=512,C=3, fp32 in/out.
// Strategy: bf16 MFMA (16x16x32), two GEMM passes via bf16 intermediate
// Y[b,k,c,w] in workspace. D (512x512) generated on device (Dh==Dw).
// R1: 2-phase prefetch + double-buffered LDS (1 barrier/k-step), A-tile
// source pre-swizzle (chunk ^= (row>>1)&3) to kill 8-way ds_read conflicts,
// launch_bounds(256,4) for 4-5 blocks/CU.

typedef __bf16 bf16_t;
typedef bf16_t bf16x8 __attribute__((ext_vector_type(8)));
typedef float  f32x4  __attribute__((ext_vector_type(4)));

__device__ __forceinline__ uint32_t f2bf(float f) {
    union { float f; uint32_t u; } v; v.f = f;
    uint32_t r = v.u + 0x7fffu + ((v.u >> 16) & 1u);   // RNE
    return r >> 16;
}

__device__ __forceinline__ f32x4 mfma16(bf16x8 a, bf16x8 b, f32x4 c) {
    return __builtin_amdgcn_mfma_f32_16x16x32_bf16(a, b, c, 0, 0, 0);
}

__device__ __forceinline__ void load_lds16(const void* g, void* l) {
    __builtin_amdgcn_global_load_lds(
        (const __attribute__((address_space(1))) uint32_t*)g,
        (__attribute__((address_space(3))) uint32_t*)l, 16, 0, 0);
}

// ---------------- D matrix generation (bf16, row-major D[k][h]) -------------
__global__ __launch_bounds__(256) void gen_dct(uint16_t* __restrict__ Dbf) {
    int idx = blockIdx.x * 256 + threadIdx.x;      // 512*512 elems
    int k = idx >> 9, h = idx & 511;
    int phase = ((2 * h + 1) * k) & 2047;          // exact mod-2048 reduction
    float ang = (float)phase * 3.0679615757712823e-3f;   // pi/1024
    float s = (k == 0) ? 0.04419417382415922f : 0.0625f; // sqrt(1/512), sqrt(2/512)
    Dbf[idx] = (uint16_t)f2bf(__cosf(ang) * s);
}

// ---------------- Pass 1: Y[b,k,c,w] = sum_h D[k,h] * x[b,h,w,c] ------------
// GEMM per b: C[m=k(128-tile), n=remapped (c,w) col (96-tile)], K=h, BK=32.
// A = D tile via global_load_lds, source chunk pre-swizzled so fragment reads
//     (chunk = (lane>>4) ^ ((row>>1)&3)) are 2-way (free).
// B = x tile fp32->bf16, transposed in-register into LDS [col][h], XOR-swizzled.
// Loop: prefetch(t+1) -> compute(t) -> pack/write B(t+1) -> barrier.
__global__ __launch_bounds__(256, 4) void pass1(const float* __restrict__ x,
                                                const uint16_t* __restrict__ Dbf,
                                                uint16_t* __restrict__ Y) {
    __shared__ __align__(16) uint16_t Alds[2][128 * 32];   // 16 KB
    __shared__ __align__(16) uint16_t Blds[2][96 * 32];    // 12 KB
    const int t = threadIdx.x;
    const int lane = t & 63, wv = t >> 6;
    const int nt = blockIdx.x;   // j-tile 0..15 (96 cols = 32 w * 3 c)
    const int mt = blockIdx.y;   // k-tile 0..3
    const int b  = blockIdx.z;
    const float* xb = x + (size_t)b * (512 * 1536);

    // A staging: slot q -> row m=q>>2, chunk slot i=q&3 holds global chunk
    // i ^ ((m>>1)&3)  (involution; read side applies the same XOR).
    const int q0 = t, q1 = t + 256;
    const int m0 = q0 >> 2, i0 = (q0 & 3) ^ ((m0 >> 1) & 3);
    const int m1 = q1 >> 2, i1 = (q1 & 3) ^ ((m1 >> 1) & 3);
    const uint16_t* Asrc0 = Dbf + (size_t)(mt * 128 + m0) * 512 + i0 * 8;
    const uint16_t* Asrc1 = Dbf + (size_t)(mt * 128 + m1) * 512 + i1 * 8;

    // B-staging mapping (threads 0..191): jl -> (w,c); col remap so that
    // MFMA col-tiles 2c/2c+1 hold even/odd w (enables paired bf16 stores).
    const int jl = t % 96;
    const int hh = t / 96;                       // 0/1 -> h-halves of 16
    const int wl = jl / 3, cc = jl - 3 * wl;
    const int ncol = cc * 32 + ((wl >> 1) + ((wl & 1) << 4));
    const int xv = (ncol >> 1) & 3;              // 16B-chunk XOR swizzle
    const int jg = nt * 96 + jl;
    const float* xsrc = xb + (size_t)(hh * 16) * 1536 + jg;

    f32x4 acc[2][6] = {};
    float v[16];

    // ---- prologue: stage kt=0 into buffer 0 ----
    load_lds16(Asrc0, &Alds[0][q0 * 8]);
    load_lds16(Asrc1, &Alds[0][q1 * 8]);
    if (t < 192) {
#pragma unroll
        for (int r = 0; r < 16; ++r) v[r] = xsrc[(size_t)r * 1536];
        uint32_t p[8];
#pragma unroll
        for (int i = 0; i < 8; ++i)
            p[i] = f2bf(v[2 * i]) | (f2bf(v[2 * i + 1]) << 16);
        *(uint4*)&Blds[0][ncol * 32 + (((hh * 2 + 0) ^ xv) << 3)] =
            make_uint4(p[0], p[1], p[2], p[3]);
        *(uint4*)&Blds[0][ncol * 32 + (((hh * 2 + 1) ^ xv) << 3)] =
            make_uint4(p[4], p[5], p[6], p[7]);
    }
    __syncthreads();

    for (int kt = 0; kt < 16; ++kt) {
        const int cur = kt & 1, nxt = cur ^ 1;

        // ---- issue prefetch of kt+1 (A direct-to-LDS, B to registers) ----
        if (kt < 15) {
            load_lds16(Asrc0 + (kt + 1) * 32, &Alds[nxt][q0 * 8]);
            load_lds16(Asrc1 + (kt + 1) * 32, &Alds[nxt][q1 * 8]);
            if (t < 192) {
                const float* s = xsrc + (size_t)(kt + 1) * 32 * 1536;
#pragma unroll
                for (int r = 0; r < 16; ++r) v[r] = s[(size_t)r * 1536];
            }
        }

        // ---- compute on buffer cur ----
        bf16x8 aq[2];
#pragma unroll
        for (int i = 0; i < 2; ++i) {
            int row = (wv * 2 + i) * 16 + (lane & 15);
            aq[i] = *(bf16x8*)&Alds[cur][row * 32 +
                        (((lane >> 4) ^ ((row >> 1) & 3)) << 3)];
        }
#pragma unroll
        for (int tt = 0; tt < 6; ++tt) {
            int col = tt * 16 + (lane & 15);
            bf16x8 bq = *(bf16x8*)&Blds[cur][col * 32 +
                        (((lane >> 4) ^ ((col >> 1) & 3)) << 3)];
            acc[0][tt] = mfma16(aq[0], bq, acc[0][tt]);
            acc[1][tt] = mfma16(aq[1], bq, acc[1][tt]);
        }

        // ---- pack + write B(kt+1) into the other buffer ----
        if (kt < 15 && t < 192) {
            uint32_t p[8];
#pragma unroll
            for (int i = 0; i < 8; ++i)
                p[i] = f2bf(v[2 * i]) | (f2bf(v[2 * i + 1]) << 16);
            *(uint4*)&Blds[nxt][ncol * 32 + (((hh * 2 + 0) ^ xv) << 3)] =
                make_uint4(p[0], p[1], p[2], p[3]);
            *(uint4*)&Blds[nxt][ncol * 32 + (((hh * 2 + 1) ^ xv) << 3)] =
                make_uint4(p[4], p[5], p[6], p[7]);
        }
        __syncthreads();
    }

    // Epilogue: direct coalesced dword stores (bf16 pair at adjacent w).
    const int wg = nt * 32 + 2 * (lane & 15);
#pragma unroll
    for (int i = 0; i < 2; ++i) {
        int kg = mt * 128 + (wv * 2 + i) * 16 + ((lane >> 4) << 2);
#pragma unroll
        for (int c = 0; c < 3; ++c)
#pragma unroll
            for (int r = 0; r < 4; ++r) {
                uint32_t pk = f2bf(acc[i][2 * c][r]) | (f2bf(acc[i][2 * c + 1][r]) << 16);
                *(uint32_t*)&Y[(size_t)b * 786432 + (size_t)(kg + r) * 1536 + c * 512 + wg] = pk;
            }
    }
}

// ---------------- Pass 2: out[b,k,l,c] = sum_w D[l,w] * Y[b,k,c,w] ----------
// GEMM per b: C[m=kc(96-tile), n=l(128-tile)], K=w, BK=32.
// Both operands staged with global_load_lds, chunk-swizzled sources.
// Same 2-phase prefetch structure; epilogue transposes in 2 l-halves so the
// LDS union stays at 28 KB (5 blocks/CU ceiling).
__global__ __launch_bounds__(256, 4) void pass2(const uint16_t* __restrict__ Y,
                                                const uint16_t* __restrict__ Dbf,
                                                float* __restrict__ out) {
    __shared__ __align__(16) char smem[28672];   // 2 x (A 6144 + B 8192)
    const int t = threadIdx.x;
    const int lane = t & 63, wv = t >> 6;
    const int lt = blockIdx.x;   // l-tile 0..3
    const int mt = blockIdx.y;   // kc-tile 0..15
    const int b  = blockIdx.z;
    const size_t yb = (size_t)b * 786432;

    // slot -> source chunk swizzle (i ^= (m>>1)&3), A: 384 slots, B: 512 slots
    const int qa0 = t;
    const int ma0 = qa0 >> 2, ia0 = (qa0 & 3) ^ ((ma0 >> 1) & 3);
    const int qa1 = t + 256;
    const int ma1 = qa1 >> 2, ia1 = (qa1 & 3) ^ ((ma1 >> 1) & 3);
    const int mb0 = ma0, ib0 = ia0;
    const int mb1 = ma1, ib1 = ia1;

    const uint16_t* As0 = Y + yb + (size_t)(mt * 96 + ma0) * 512 + ia0 * 8;
    const uint16_t* As1 = Y + yb + (size_t)(mt * 96 + ma1) * 512 + ia1 * 8;
    const uint16_t* Bs0 = Dbf + (size_t)(lt * 128 + mb0) * 512 + ib0 * 8;
    const uint16_t* Bs1 = Dbf + (size_t)(lt * 128 + mb1) * 512 + ib1 * 8;

    f32x4 acc[6][2] = {};

    auto stage = [&](int kt, int buf) {
        uint16_t* Al = (uint16_t*)(smem + buf * 14336);
        uint16_t* Bl = (uint16_t*)(smem + buf * 14336 + 6144);
        load_lds16(As0 + kt * 32, Al + qa0 * 8);
        if (t < 128) load_lds16(As1 + kt * 32, Al + qa1 * 8);
        load_lds16(Bs0 + kt * 32, Bl + qa0 * 8);
        load_lds16(Bs1 + kt * 32, Bl + qa1 * 8);
    };

    stage(0, 0);
    __syncthreads();

    for (int kt = 0; kt < 16; ++kt) {
        const int cur = kt & 1;
        if (kt < 15) stage(kt + 1, cur ^ 1);

        const uint16_t* Al = (const uint16_t*)(smem + cur * 14336);
        const uint16_t* Bl = (const uint16_t*)(smem + cur * 14336 + 6144);

        bf16x8 bq[2];
#pragma unroll
        for (int p = 0; p < 2; ++p) {
            int row = (wv * 2 + p) * 16 + (lane & 15);
            bq[p] = *(bf16x8*)&Bl[row * 32 +
                        (((lane >> 4) ^ ((row >> 1) & 3)) << 3)];
        }
#pragma unroll
        for (int tt = 0; tt < 6; ++tt) {
            int row = tt * 16 + (lane & 15);
            bf16x8 aq = *(bf16x8*)&Al[row * 32 +
                        (((lane >> 4) ^ ((row >> 1) & 3)) << 3)];
            acc[tt][0] = mfma16(aq, bq[0], acc[tt][0]);
            acc[tt][1] = mfma16(aq, bq[1], acc[tt][1]);
        }
        __syncthreads();
    }

    // Epilogue: transpose [kc][l] -> out rows [k][(l,c)] in two l-halves
    // via padded LDS (96 x 65 fp32 = 24.96 KB, fits the 28 KB union).
    float* El = (float*)smem;
    const int kloc = t >> 3, sub = t & 7;   // 32 k-rows, 8 threads per row
#pragma unroll
    for (int hf = 0; hf < 2; ++hf) {
        __syncthreads();
        if ((wv >> 1) == hf) {              // waves owning l in [hf*64, hf*64+64)
#pragma unroll
            for (int tt = 0; tt < 6; ++tt)
#pragma unroll
                for (int p = 0; p < 2; ++p) {
                    int m = tt * 16 + ((lane >> 4) << 2);
                    int lc = ((wv & 1) * 2 + p) * 16 + (lane & 15);  // local l
#pragma unroll
                    for (int r = 0; r < 4; ++r)
                        El[(m + r) * 65 + lc] = acc[tt][p][r];
                }
        }
        __syncthreads();
        size_t ob = (size_t)b * 786432 + (size_t)(mt * 32 + kloc) * 1536 +
                    lt * 384 + hf * 192 + sub * 24;
#pragma unroll
        for (int q = 0; q < 6; ++q) {
            int o0 = hf * 192 + sub * 24 + q * 4;
            float4 v;
            v.x = El[(kloc * 3 + ((o0 + 0) % 3)) * 65 + ((o0 + 0) / 3 - hf * 64)];
            v.y = El[(kloc * 3 + ((o0 + 1) % 3)) * 65 + ((o0 + 1) / 3 - hf * 64)];
            v.z = El[(kloc * 3 + ((o0 + 2) % 3)) * 65 + ((o0 + 2) / 3 - hf * 64)];
            v.w = El[(kloc * 3 + ((o0 + 3) % 3)) * 65 + ((o0 + 3) / 3 - hf * 64)];
            *(float4*)&out[ob + q * 4] = v;
        }
    }
}

// ---------------------------------------------------------------------------
extern "C" void kernel_launch(void* const* d_in, const int* in_sizes, int n_in,
                              void* d_out, int out_size, void* d_ws, size_t ws_size,
                              hipStream_t stream) {
    (void)in_sizes; (void)n_in; (void)out_size; (void)ws_size;
    const float* x = (const float*)d_in[0];
    float* out = (float*)d_out;
    uint16_t* Dbf = (uint16_t*)d_ws;                 // 512*512 bf16 = 512 KB
    uint16_t* Y   = (uint16_t*)d_ws + 512 * 512;     // 32*512*512*3 bf16 = 48 MB

    gen_dct<<<1024, 256, 0, stream>>>(Dbf);
    dim3 g1(16, 4, 32);
    pass1<<<g1, 256, 0, stream>>>(x, Dbf, Y);
    dim3 g2(4, 16, 32);
    pass2<<<g2, 256, 0, stream>>>(Y, Dbf, out);
}